// Round 13
// baseline (225.127 us; speedup 1.0000x reference)
//
#include <hip/hip_runtime.h>
#include <hip/hip_bf16.h>

static constexpr int C  = 21;
static constexpr int H  = 384;
static constexpr int W  = 384;
static constexpr int HW = H * W;
static constexpr float NCLIQ = 5.0f;

typedef unsigned short u16;
typedef unsigned int   u32;

// function-local constexpr taps: exp(-o^2/18), o=-6..6 — folds to immediates
#define GKDEF constexpr float gk[13] = { \
    0.13533528f, 0.24935222f, 0.41111229f, 0.60653066f, 0.80073740f, \
    0.94595947f, 1.00000000f, 0.94595947f, 0.80073740f, 0.60653066f, \
    0.41111229f, 0.24935222f, 0.13533528f }

__device__ __forceinline__ float bfu2f(u16 u) {
    return __uint_as_float(((u32)u) << 16);
}
__device__ __forceinline__ u16 f2bfu(float f) {
    unsigned x = __float_as_uint(f);
    return (u16)((x + 0x7FFF + ((x >> 16) & 1)) >> 16);   // RNE; inputs finite
}

// channel-range matvec + bf16 store; per-channel k-order identical to the
// full version -> bit-identical results regardless of the [CB,CE) split.
template<int CB, int CE>
__device__ __forceinline__ void st_matvec(const float* __restrict__ M,
                                          const float* v, float inv,
                                          u16* __restrict__ t, int p) {
    float a[CE - CB];
#pragma unroll
    for (int c = CB; c < CE; c++) a[c - CB] = 0.f;
#pragma unroll
    for (int k = 0; k < C; k++) {
        float e = v[k];
#pragma unroll
        for (int c = CB; c < CE; c++) a[c - CB] += M[c * C + k] * e;
    }
#pragma unroll
    for (int c = CB; c < CE; c++) t[c * HW + p] = f2bfu(a[c - CB] * inv);
}

// ---- prep: q/un planar + wtab + norms + msum + M + eq-flag + ST(it 0) ------
// R12 form: role-split 2 thr/px + rgb LDS stage. (R12 ~neutral vs R10; kept.)
__global__ __launch_bounds__(256)
void k_prep(const float* __restrict__ un, const float* __restrict__ rgb,
            const int* __restrict__ sp,
            const float* __restrict__ Wsp, const float* __restrict__ Wbi,
            const float* __restrict__ Cm,
            float* __restrict__ q, float* __restrict__ unp,
            u16* __restrict__ wtab, float* __restrict__ msum,
            float* __restrict__ inv_sp, float* __restrict__ inv_bn,
            float* __restrict__ M1, float* __restrict__ M2,
            int* __restrict__ mflag,
            u16* __restrict__ t1, u16* __restrict__ t2) {
    GKDEF;
    __shared__ float sM1[C * C], sM2[C * C];
    __shared__ float Aun[128 * C];          // coalesced un stage (10752 B)
    __shared__ float Argb[5 * 408];         // 5 rgb rows x 136 cols (8160 B)
    __shared__ int seq;
    if (threadIdx.x == 0) seq = 1;
    bool bad = false;
    for (int i = threadIdx.x; i < C * C; i += 256) {
        int c = i / C, k = i - c * C;
        float a1 = 0.f, a2 = 0.f;
        for (int j = 0; j < C; j++) {
            float cm = Cm[c * C + j];
            a1 += cm * Wsp[j * C + k];
            a2 += cm * Wbi[j * C + k];
        }
        sM1[i] = a1;
        sM2[i] = a2;
        if (__float_as_uint(a1) != __float_as_uint(a2)) bad = true;
        if (blockIdx.x == 0) { M1[i] = a1; M2[i] = a2; }
    }

    int bid = blockIdx.x;                       // 1152, XCD-swizzled
    int chunk = (bid & 7) * 144 + (bid >> 3);
    int p0 = chunk * 128;
    int px = threadIdx.x & 127;
    int half = threadIdx.x >> 7;                // 0 = A-role, 1 = B-role
    int p = p0 + px;
    int y0row = p0 / W;                         // block-uniform pixel row
    int col0 = p0 - y0row * W;                  // 0, 128, or 256
    int y = y0row, x = col0 + px;

    // stage un[p0*C .. (p0+128)*C) via coalesced float4
    {
        const float* ub = un + (size_t)p0 * C;
        for (int i = threadIdx.x; i < 128 * C / 4; i += 256)
            *(float4*)(Aun + i * 4) = *(const float4*)(ub + i * 4);
    }
    // stage rgb rows y0row-2..y0row+2, col span [col0-4, col0+132).
    for (int i = threadIdx.x; i < 5 * 102; i += 256) {
        int r = i / 102, f4 = i - r * 102;
        int gy = y0row - 2 + r;
        if (gy < 0 || gy >= H) continue;
        int gf = (col0 - 4) * 3 + f4 * 4;           // multiple of 4
        int gfc = min(max(gf, 0), W * 3 - 4);       // aligned clamp
        *(float4*)(Argb + r * 408 + f4 * 4) =
            *(const float4*)(rgb + (size_t)gy * (W * 3) + gfc);
    }
    __syncthreads();
    if (bad) atomicAnd(&seq, 0);
    __syncthreads();
    bool eq = (seq != 0);
    if (bid == 0 && threadIdx.x == 0) mflag[0] = eq ? 1 : 0;

    float v[C];
#pragma unroll
    for (int c = 0; c < C; c++)
        v[c] = Aun[px * C + c];              // stride 21 (odd) -> conflict-free

    if (half == 0) {
        // ---- A-role: planarize + wtab + norms + msum ----
#pragma unroll
        for (int c = 0; c < C; c++) {
            q[c * HW + p] = v[c];
            unp[c * HW + p] = v[c];
        }
        float swl[9];
#pragma unroll
        for (int i = 0; i < 9; i++) swl[i] = expf(-(float)i * (1.0f / 51200.0f));

        int xb = x - col0 + 4;                  // own col within the 136-span
        float r0 = Argb[2 * 408 + xb * 3 + 0];
        float g0 = Argb[2 * 408 + xb * 3 + 1];
        float b0 = Argb[2 * 408 + xb * 3 + 2];
        float s = 0.f;
        int t = 0;
#pragma unroll
        for (int dy = -2; dy <= 2; dy++) {
#pragma unroll
            for (int dx = -2; dx <= 2; dx++, t++) {
                int sy = y - dy, sx = x - dx;
                float wv = 0.f;
                if (sy >= 0 && sy < H && sx >= 0 && sx < W) {
                    int lr = 2 - dy;            // staged row (0..4)
                    const float* rp = Argb + lr * 408 + (sx - col0 + 4) * 3;
                    float dr = r0 - rp[0];
                    float dg = g0 - rp[1];
                    float db = b0 - rp[2];
                    wv = swl[dy * dy + dx * dx] *
                         expf(-(dr * dr + dg * dg + db * db) * (1.0f / 18.0f));
                }
                u16 wu = f2bfu(wv);
                wtab[(size_t)t * HW + p] = wu;
                s += bfu2f(wu);
            }
        }
        inv_bn[p] = 1.0f / s;

        float fy = 0.f, fx = 0.f;
        for (int o = -6; o <= 6; o++) {
            if (y - o >= 0 && y - o < H) fy += gk[o + 6];
            if (x - o >= 0 && x - o < W) fx += gk[o + 6];
        }
        inv_sp[p] = 1.0f / (fy * fx);

        int vv = sp[x * W + y];   // sp_map transposed: sp[x][y]
        msum[p] = (vv == 5 || vv == 37 || vv == 81 || vv == 150 || vv == 230)
                      ? 1.0f : 0.0f;
    } else {
        // ---- B-role: fused ST for iteration 0 ----
        float mx = -1e30f;
#pragma unroll
        for (int c = 0; c < C; c++) mx = fmaxf(mx, v[c]);
        float ssum = 0.f;
#pragma unroll
        for (int c = 0; c < C; c++) {
            v[c] = expf(v[c] - mx);
            ssum += v[c];
        }
        float inv = 1.0f / ssum;
        st_matvec<0, C>(sM1, v, inv, t1, p);
        if (!eq)                 // general path; skipped on graded instance
            st_matvec<0, C>(sM2, v, inv, t2, p);
    }
}

// fused softmax + 21x21 matvec(s) (iters 1..4). R10 form (confirmed):
// 2 thr/px, matmul split by channel range, M via uniform s_loads.
__global__ __launch_bounds__(256)
void k_ST(const float* __restrict__ q, const float* __restrict__ M1,
          const float* __restrict__ M2, const int* __restrict__ mflag,
          u16* __restrict__ t1, u16* __restrict__ t2) {
    int bid = blockIdx.x;                  // 1152, XCD-swizzled
    int chunk = (bid & 7) * 144 + (bid >> 3);
    int p = chunk * 128 + (threadIdx.x & 127);
    int half = threadIdx.x >> 7;           // wave-uniform
    bool meq = (mflag[0] != 0);            // uniform branch
    float v[C];
    float mx = -1e30f;
#pragma unroll
    for (int c = 0; c < C; c++) {
        v[c] = q[c * HW + p];
        mx = fmaxf(mx, v[c]);
    }
    float s = 0.f;
#pragma unroll
    for (int c = 0; c < C; c++) {
        v[c] = expf(v[c] - mx);
        s += v[c];
    }
    float inv = 1.0f / s;
    if (half == 0) {
        st_matvec<0, 11>(M1, v, inv, t1, p);
        if (!meq) st_matvec<0, 11>(M2, v, inv, t2, p);
    } else {
        st_matvec<11, C>(M1, v, inv, t1, p);
        if (!meq) st_matvec<11, C>(M2, v, inv, t2, p);
    }
}

// fused separable blur (LDS) + bilateral + update. R5/R10 body.
// R13: __launch_bounds__(256, 6) caps VGPR at 85 -> 6 blocks/CU resident
// (24 waves/CU vs 20 at VGPR~96). Pure occupancy lever: zero change to
// memory ops / arithmetic / geometry. To make 85 reachable without spills,
// the 6 update-phase float4 loads are moved AFTER the bilateral (were
// hoisted; ~24 fewer live VGPRs across the 100-FMA bilateral chain; their
// tail latency is covered by the added waves). Bit-identical output.
__global__ __launch_bounds__(256, 6)
void k_VF(const u16* __restrict__ t1, const u16* __restrict__ t2,
          const u16* __restrict__ wtab, const float* __restrict__ msum,
          const float* __restrict__ inv_sp, const float* __restrict__ inv_bn,
          const float* __restrict__ unp,
          const float* __restrict__ loww, const float* __restrict__ highw,
          const int* __restrict__ mflag,
          float* __restrict__ q, float* __restrict__ outp) {
    GKDEF;
    __shared__ float A[20 * 144];   // t1 halo tile; reused for t2 iff !meq
    __shared__ float B[8 * 144];    // blurV output
    int bid = blockIdx.x;           // grid 3024, XCD-swizzled
    int xcd = bid & 7;
    int idx = bid >> 3;
    int c   = idx % 21;
    int rem = idx / 21;
    int xt  = rem % 3;
    int ytl = rem / 3;
    int gyt = xcd * 6 + ytl;
    int x0 = xt * 128;
    int y0 = gyt * 8;
    bool meq = (mflag[0] != 0);     // uniform branch
    const u16* t1p = t1 + (size_t)c * HW;

    // ---- stage A = t1 halo (zero-padded), bf16 -> fp32 ----
    for (int i = threadIdx.x; i < 20 * 36; i += 256) {
        int r = i / 36, q4 = i - r * 36;
        int gy = y0 - 6 + r;
        int gx = x0 - 8 + q4 * 4;
        float4 v;
        if (gy < 0 || gy >= H) {
            v.x = v.y = v.z = v.w = 0.f;
        } else if (gx >= 0 && gx + 3 < W) {
            ushort4 u = *(const ushort4*)(t1p + gy * W + gx);
            v.x = bfu2f(u.x); v.y = bfu2f(u.y); v.z = bfu2f(u.z); v.w = bfu2f(u.w);
        } else {
            float e[4];
            for (int jj = 0; jj < 4; jj++) {
                int xx = gx + jj;
                e[jj] = (xx >= 0 && xx < W) ? bfu2f(t1p[gy * W + xx]) : 0.f;
            }
            v.x = e[0]; v.y = e[1]; v.z = e[2]; v.w = e[3];
        }
        *(float4*)(A + r * 144 + q4 * 4) = v;
    }
    __syncthreads();

    // ---- blurV (float4): B[r][c4..c4+3] = sum_d gk[d]*A[r+d][c4..c4+3] ----
    for (int i = threadIdx.x; i < 8 * 36; i += 256) {
        int r = i / 36, c4 = (i - r * 36) * 4;
        float ax = 0.f, ay = 0.f, az = 0.f, aw = 0.f;
#pragma unroll
        for (int d = 0; d < 13; d++) {
            const float4 av = *(const float4*)(A + (r + d) * 144 + c4);
            ax += gk[d] * av.x;
            ay += gk[d] * av.y;
            az += gk[d] * av.z;
            aw += gk[d] * av.w;
        }
        float4 o;
        o.x = ax; o.y = ay; o.z = az; o.w = aw;
        *(float4*)(B + r * 144 + c4) = o;
    }
    __syncthreads();

    int row = threadIdx.x >> 5;
    int xq  = (threadIdx.x & 31) * 4;
    int y   = y0 + row;
    int x4  = x0 + xq;
    int p4  = y * W + x4;

    // ---- blurH: 20-float window as 5 aligned b128 (conflict-free) ----
    float bw[20];
    {
        const float* bp = B + row * 144 + xq;
        *(float4*)(bw +  0) = *(const float4*)(bp +  0);
        *(float4*)(bw +  4) = *(const float4*)(bp +  4);
        *(float4*)(bw +  8) = *(const float4*)(bp +  8);
        *(float4*)(bw + 12) = *(const float4*)(bp + 12);
        *(float4*)(bw + 16) = *(const float4*)(bp + 16);
    }
    float sp_[4];
#pragma unroll
    for (int jj = 0; jj < 4; jj++) {
        float a = 0.f;
#pragma unroll
        for (int t = 0; t < 13; t++) a += gk[t] * bw[jj + t + 2];
        sp_[jj] = a;
    }

    int robase;   // bilateral row base in A
    if (meq) {
        robase = row + 6;     // t1 halo rows: gy = y0-6+r  -> r = row-dy+6
    } else {
        // ---- general path: stage t2 tile into A (after blurV barrier) ----
        const u16* t2p = t2 + (size_t)c * HW;
        for (int i = threadIdx.x; i < 12 * 36; i += 256) {
            int r = i / 36, q4 = i - r * 36;
            int gy = min(max(y0 - 2 + r, 0), H - 1);      // clamped; OOB wt 0
            int gx = min(max(x0 - 8 + q4 * 4, 0), W - 4); // clamped; OOB wt 0
            ushort4 u = *(const ushort4*)(t2p + gy * W + gx);
            float4 v;
            v.x = bfu2f(u.x); v.y = bfu2f(u.y); v.z = bfu2f(u.z); v.w = bfu2f(u.w);
            *(float4*)(A + r * 144 + q4 * 4) = v;
        }
        __syncthreads();
        robase = row + 2;     // t2 tile rows: gy = y0-2+r  -> r = row-dy+2
    }

    // ---- bilateral from LDS; wtab loads rolled per-dy ----
    float bi[4] = {0.f, 0.f, 0.f, 0.f};
    int lb = xq + 8;                        // local col of x4 in the 144-tile
#pragma unroll
    for (int dy = -2; dy <= 2; dy++) {
        int tb = (dy + 2) * 5;
        ushort4 wv0 = *(const ushort4*)(wtab + (size_t)(tb + 0) * HW + p4);
        ushort4 wv1 = *(const ushort4*)(wtab + (size_t)(tb + 1) * HW + p4);
        ushort4 wv2 = *(const ushort4*)(wtab + (size_t)(tb + 2) * HW + p4);
        ushort4 wv3 = *(const ushort4*)(wtab + (size_t)(tb + 3) * HW + p4);
        ushort4 wv4 = *(const ushort4*)(wtab + (size_t)(tb + 4) * HW + p4);
        const ushort4 wvs[5] = {wv0, wv1, wv2, wv3, wv4};
        int r = robase - dy;
        float rr[12];
        float4 v0 = *(const float4*)(A + r * 144 + lb - 4);
        float4 v1 = *(const float4*)(A + r * 144 + lb);
        float4 v2 = *(const float4*)(A + r * 144 + lb + 4);
        rr[0] = v0.x; rr[1] = v0.y; rr[2]  = v0.z; rr[3]  = v0.w;
        rr[4] = v1.x; rr[5] = v1.y; rr[6]  = v1.z; rr[7]  = v1.w;
        rr[8] = v2.x; rr[9] = v2.y; rr[10] = v2.z; rr[11] = v2.w;
#pragma unroll
        for (int dx = -2; dx <= 2; dx++) {
            const ushort4 wv = wvs[dx + 2];
            bi[0] += bfu2f(wv.x) * rr[0 - dx + 4];
            bi[1] += bfu2f(wv.y) * rr[1 - dx + 4];
            bi[2] += bfu2f(wv.z) * rr[2 - dx + 4];
            bi[3] += bfu2f(wv.w) * rr[3 - dx + 4];
        }
    }

    // ---- update-phase loads (post-bilateral: shorter live ranges) ----
    float lc = loww[c], hw_ = highw[0];
    float4 msv = *(const float4*)(msum + p4);
    float4 isv = *(const float4*)(inv_sp + p4);
    float4 ibv = *(const float4*)(inv_bn + p4);
    float4 unv = *(const float4*)(unp + (size_t)c * HW + p4);
    float* qp = q + (size_t)c * HW + p4;
    float4 qo4 = *(const float4*)qp;

    // ---- update: q/out = un - pairwise + superpixel closed form ----
    float msa[4] = {msv.x, msv.y, msv.z, msv.w};
    float isa[4] = {isv.x, isv.y, isv.z, isv.w};
    float iba[4] = {ibv.x, ibv.y, ibv.z, ibv.w};
    float qoa[4] = {qo4.x, qo4.y, qo4.z, qo4.w};
    float una[4] = {unv.x, unv.y, unv.z, unv.w};
    float outv[4];
    for (int jj = 0; jj < 4; jj++) {
        float pw = sp_[jj] * isa[jj] + bi[jj] * iba[jj];
        float qo = qoa[jj];
        float ft = (msa[jj] * qo + (NCLIQ - msa[jj])) / qo;
        float su = lc * ft + hw_ * (1.0f - ft);
        outv[jj] = una[jj] - pw + su;
    }
    if (outp) {   // last iteration: write final (H,W,C) layout directly
        for (int jj = 0; jj < 4; jj++)
            outp[(size_t)(p4 + jj) * C + c] = outv[jj];
    } else {
        float4 res;
        res.x = outv[0]; res.y = outv[1]; res.z = outv[2]; res.w = outv[3];
        *(float4*)qp = res;
    }
}

// ---- launch -----------------------------------------------------------------

extern "C" void kernel_launch(void* const* d_in, const int* in_sizes, int n_in,
                              void* d_out, int out_size, void* d_ws, size_t ws_size,
                              hipStream_t stream) {
    const float* un    = (const float*)d_in[0];
    const float* rgb   = (const float*)d_in[1];
    const int*   sp    = (const int*)d_in[2];
    const float* Wsp   = (const float*)d_in[3];
    const float* Wbi   = (const float*)d_in[4];
    const float* Cm    = (const float*)d_in[5];
    const float* loww  = (const float*)d_in[6];
    const float* highw = (const float*)d_in[7];
    float* out = (float*)d_out;

    // ws layout ~46.5 MB
    float* ws    = (float*)d_ws;
    float* q     = ws;                            // C*HW fp32
    float* unp   = q   + (size_t)C * HW;          // C*HW fp32
    float* msum  = unp + (size_t)C * HW;          // HW
    float* isp   = msum + HW;                     // HW
    float* ibn   = isp + HW;                      // HW
    float* M1    = ibn + HW;                      // C*C
    float* M2    = M1 + C * C;                    // C*C
    int*   mflag = (int*)(M2 + C * C);            // 1 (in old pad space)
    u16*   t1    = (u16*)(M2 + C * C + 6);        // C*HW bf16 (8B-aligned)
    u16*   t2    = t1 + (size_t)C * HW;           // C*HW bf16
    u16*   wtab  = t2 + (size_t)C * HW;           // 25*HW bf16

    dim3 blk(256);
    dim3 gpix(HW / 128);                 // 1152, 128 px/block, 2 thr/px
    dim3 gVF(3 * 48 * C);                // 3024, 1-D swizzled (R5 form)

    // prep includes iteration 0's ST (B-waves)
    k_prep<<<gpix, blk, 0, stream>>>(un, rgb, sp, Wsp, Wbi, Cm,
                                     q, unp, wtab, msum, isp, ibn, M1, M2,
                                     mflag, t1, t2);
    for (int it = 0; it < 5; it++) {
        k_VF<<<gVF, blk, 0, stream>>>(t1, t2, wtab, msum, isp, ibn,
                                      unp, loww, highw, mflag, q,
                                      (it == 4) ? out : (float*)nullptr);
        if (it < 4)
            k_ST<<<gpix, blk, 0, stream>>>(q, M1, M2, mflag, t1, t2);
    }
}

// Round 14
// 203.729 us; speedup vs baseline: 1.1050x; 1.1050x over previous
//
#include <hip/hip_runtime.h>
#include <hip/hip_bf16.h>

static constexpr int C  = 21;
static constexpr int H  = 384;
static constexpr int W  = 384;
static constexpr int HW = H * W;
static constexpr float NCLIQ = 5.0f;

typedef unsigned short u16;
typedef unsigned int   u32;

// function-local constexpr taps: exp(-o^2/18), o=-6..6 — folds to immediates
#define GKDEF constexpr float gk[13] = { \
    0.13533528f, 0.24935222f, 0.41111229f, 0.60653066f, 0.80073740f, \
    0.94595947f, 1.00000000f, 0.94595947f, 0.80073740f, 0.60653066f, \
    0.41111229f, 0.24935222f, 0.13533528f }

__device__ __forceinline__ float bfu2f(u16 u) {
    return __uint_as_float(((u32)u) << 16);
}
__device__ __forceinline__ u16 f2bfu(float f) {
    unsigned x = __float_as_uint(f);
    return (u16)((x + 0x7FFF + ((x >> 16) & 1)) >> 16);   // RNE; inputs finite
}
// unpack one bf16 from a tap-pair u32 (sel 0 = low/even tap, 1 = high/odd)
__device__ __forceinline__ float pair2f(u32 w, int sel) {
    return __uint_as_float(sel ? (w & 0xFFFF0000u) : (w << 16));
}

// channel-range matvec + bf16 store; per-channel k-order identical to the
// full version -> bit-identical results regardless of the [CB,CE) split.
template<int CB, int CE>
__device__ __forceinline__ void st_matvec(const float* __restrict__ M,
                                          const float* v, float inv,
                                          u16* __restrict__ t, int p) {
    float a[CE - CB];
#pragma unroll
    for (int c = CB; c < CE; c++) a[c - CB] = 0.f;
#pragma unroll
    for (int k = 0; k < C; k++) {
        float e = v[k];
#pragma unroll
        for (int c = CB; c < CE; c++) a[c - CB] += M[c * C + k] * e;
    }
#pragma unroll
    for (int c = CB; c < CE; c++) t[c * HW + p] = f2bfu(a[c - CB] * inv);
}

// M == -I shortcut: full matvec yields a1[c] = -e_c EXACTLY when M is
// bitwise -I (off-diag products are +-0, accumulate to +-0, x+(+-0)=x for
// x!=0), and (-e)*inv == -(e*inv) bitwise -> skipping is bit-identical.
template<int CB, int CE>
__device__ __forceinline__ void st_negI(const float* v, float inv,
                                        u16* __restrict__ t, int p) {
#pragma unroll
    for (int c = CB; c < CE; c++) t[c * HW + p] = f2bfu(-(v[c] * inv));
}

// ---- prep: q/un planar + wtab + norms + msum + M + flag + ST(it 0) ---------
// R12 role-split form. R14: wtab written as 13 tap-pair u32 streams; flag
// gains negI detection (2 = eq && M1 == -I bitwise).
__global__ __launch_bounds__(256)
void k_prep(const float* __restrict__ un, const float* __restrict__ rgb,
            const int* __restrict__ sp,
            const float* __restrict__ Wsp, const float* __restrict__ Wbi,
            const float* __restrict__ Cm,
            float* __restrict__ q, float* __restrict__ unp,
            u32* __restrict__ wtab, float* __restrict__ msum,
            float* __restrict__ inv_sp, float* __restrict__ inv_bn,
            float* __restrict__ M1, float* __restrict__ M2,
            int* __restrict__ mflag,
            u16* __restrict__ t1, u16* __restrict__ t2) {
    GKDEF;
    __shared__ float sM1[C * C], sM2[C * C];
    __shared__ float Aun[128 * C];          // coalesced un stage (10752 B)
    __shared__ float Argb[5 * 408];         // 5 rgb rows x 136 cols (8160 B)
    __shared__ int seq, sneg;
    if (threadIdx.x == 0) { seq = 1; sneg = 1; }
    bool bad = false, nneg = false;
    for (int i = threadIdx.x; i < C * C; i += 256) {
        int c = i / C, k = i - c * C;
        float a1 = 0.f, a2 = 0.f;
        for (int j = 0; j < C; j++) {
            float cm = Cm[c * C + j];
            a1 += cm * Wsp[j * C + k];
            a2 += cm * Wbi[j * C + k];
        }
        sM1[i] = a1;
        sM2[i] = a2;
        u32 b = __float_as_uint(a1);
        if (b != __float_as_uint(a2)) bad = true;
        if (c == k ? (b != 0xBF800000u) : ((b & 0x7FFFFFFFu) != 0u)) nneg = true;
        if (blockIdx.x == 0) { M1[i] = a1; M2[i] = a2; }
    }

    int bid = blockIdx.x;                       // 1152, XCD-swizzled
    int chunk = (bid & 7) * 144 + (bid >> 3);
    int p0 = chunk * 128;
    int px = threadIdx.x & 127;
    int half = threadIdx.x >> 7;                // 0 = A-role, 1 = B-role
    int p = p0 + px;
    int y0row = p0 / W;                         // block-uniform pixel row
    int col0 = p0 - y0row * W;                  // 0, 128, or 256
    int y = y0row, x = col0 + px;

    // stage un[p0*C .. (p0+128)*C) via coalesced float4
    {
        const float* ub = un + (size_t)p0 * C;
        for (int i = threadIdx.x; i < 128 * C / 4; i += 256)
            *(float4*)(Aun + i * 4) = *(const float4*)(ub + i * 4);
    }
    // stage rgb rows y0row-2..y0row+2, col span [col0-4, col0+132).
    for (int i = threadIdx.x; i < 5 * 102; i += 256) {
        int r = i / 102, f4 = i - r * 102;
        int gy = y0row - 2 + r;
        if (gy < 0 || gy >= H) continue;
        int gf = (col0 - 4) * 3 + f4 * 4;           // multiple of 4
        int gfc = min(max(gf, 0), W * 3 - 4);       // aligned clamp
        *(float4*)(Argb + r * 408 + f4 * 4) =
            *(const float4*)(rgb + (size_t)gy * (W * 3) + gfc);
    }
    __syncthreads();
    if (bad)  atomicAnd(&seq, 0);
    if (nneg) atomicAnd(&sneg, 0);
    __syncthreads();
    bool eq   = (seq != 0);
    bool negI = eq && (sneg != 0);
    if (bid == 0 && threadIdx.x == 0) mflag[0] = negI ? 2 : (eq ? 1 : 0);

    float v[C];
#pragma unroll
    for (int c = 0; c < C; c++)
        v[c] = Aun[px * C + c];              // stride 21 (odd) -> conflict-free

    if (half == 0) {
        // ---- A-role: planarize + wtab + norms + msum ----
#pragma unroll
        for (int c = 0; c < C; c++) {
            q[c * HW + p] = v[c];
            unp[c * HW + p] = v[c];
        }
        float swl[9];
#pragma unroll
        for (int i = 0; i < 9; i++) swl[i] = expf(-(float)i * (1.0f / 51200.0f));

        int xb = x - col0 + 4;                  // own col within the 136-span
        float r0 = Argb[2 * 408 + xb * 3 + 0];
        float g0 = Argb[2 * 408 + xb * 3 + 1];
        float b0 = Argb[2 * 408 + xb * 3 + 2];
        u32 pw[13];
#pragma unroll
        for (int i = 0; i < 13; i++) pw[i] = 0u;
        float s = 0.f;
        int t = 0;
#pragma unroll
        for (int dy = -2; dy <= 2; dy++) {
#pragma unroll
            for (int dx = -2; dx <= 2; dx++, t++) {
                int sy = y - dy, sx = x - dx;
                float wv = 0.f;
                if (sy >= 0 && sy < H && sx >= 0 && sx < W) {
                    int lr = 2 - dy;            // staged row (0..4)
                    const float* rp = Argb + lr * 408 + (sx - col0 + 4) * 3;
                    float dr = r0 - rp[0];
                    float dg = g0 - rp[1];
                    float db = b0 - rp[2];
                    wv = swl[dy * dy + dx * dx] *
                         expf(-(dr * dr + dg * dg + db * db) * (1.0f / 18.0f));
                }
                u16 wu = f2bfu(wv);
                pw[t >> 1] |= ((u32)wu) << ((t & 1) * 16);  // static idx
                s += bfu2f(wu);
            }
        }
#pragma unroll
        for (int i = 0; i < 13; i++)
            wtab[(size_t)i * HW + p] = pw[i];   // 13 coalesced u32 stores
        inv_bn[p] = 1.0f / s;

        float fy = 0.f, fx = 0.f;
        for (int o = -6; o <= 6; o++) {
            if (y - o >= 0 && y - o < H) fy += gk[o + 6];
            if (x - o >= 0 && x - o < W) fx += gk[o + 6];
        }
        inv_sp[p] = 1.0f / (fy * fx);

        int vv = sp[x * W + y];   // sp_map transposed: sp[x][y]
        msum[p] = (vv == 5 || vv == 37 || vv == 81 || vv == 150 || vv == 230)
                      ? 1.0f : 0.0f;
    } else {
        // ---- B-role: fused ST for iteration 0 ----
        float mx = -1e30f;
#pragma unroll
        for (int c = 0; c < C; c++) mx = fmaxf(mx, v[c]);
        float ssum = 0.f;
#pragma unroll
        for (int c = 0; c < C; c++) {
            v[c] = expf(v[c] - mx);
            ssum += v[c];
        }
        float inv = 1.0f / ssum;
        if (negI) {
            st_negI<0, C>(v, inv, t1, p);       // graded instance
        } else if (eq) {
            st_matvec<0, C>(sM1, v, inv, t1, p);
        } else {
            st_matvec<0, C>(sM1, v, inv, t1, p);
            st_matvec<0, C>(sM2, v, inv, t2, p);
        }
    }
}

// fused softmax + 21x21 matvec(s) (iters 1..4). R10 form + negI shortcut.
__global__ __launch_bounds__(256)
void k_ST(const float* __restrict__ q, const float* __restrict__ M1,
          const float* __restrict__ M2, const int* __restrict__ mflag,
          u16* __restrict__ t1, u16* __restrict__ t2) {
    int bid = blockIdx.x;                  // 1152, XCD-swizzled
    int chunk = (bid & 7) * 144 + (bid >> 3);
    int p = chunk * 128 + (threadIdx.x & 127);
    int half = threadIdx.x >> 7;           // wave-uniform
    int f = mflag[0];                      // uniform branch
    float v[C];
    float mx = -1e30f;
#pragma unroll
    for (int c = 0; c < C; c++) {
        v[c] = q[c * HW + p];
        mx = fmaxf(mx, v[c]);
    }
    float s = 0.f;
#pragma unroll
    for (int c = 0; c < C; c++) {
        v[c] = expf(v[c] - mx);
        s += v[c];
    }
    float inv = 1.0f / s;
    if (f == 2) {                          // graded instance: M == -I
        if (half == 0) st_negI<0, 11>(v, inv, t1, p);
        else           st_negI<11, C>(v, inv, t1, p);
    } else if (f == 1) {
        if (half == 0) st_matvec<0, 11>(M1, v, inv, t1, p);
        else           st_matvec<11, C>(M1, v, inv, t1, p);
    } else {
        if (half == 0) {
            st_matvec<0, 11>(M1, v, inv, t1, p);
            st_matvec<0, 11>(M2, v, inv, t2, p);
        } else {
            st_matvec<11, C>(M1, v, inv, t1, p);
            st_matvec<11, C>(M2, v, inv, t2, p);
        }
    }
}

// fused separable blur (LDS) + bilateral + update. R5/R10 body.
// R14: bilateral weights read as tap-PAIR u32 streams ([13][HW]): each dy
// row needs taps 5dy..5dy+4 -> 3 uint4 loads (pairs PR..PR+2). 25 -> 15
// wtab loads/thread, same bytes, same tap order/FMA order (bit-identical).
__global__ __launch_bounds__(256)
void k_VF(const u16* __restrict__ t1, const u16* __restrict__ t2,
          const u32* __restrict__ wtab, const float* __restrict__ msum,
          const float* __restrict__ inv_sp, const float* __restrict__ inv_bn,
          const float* __restrict__ unp,
          const float* __restrict__ loww, const float* __restrict__ highw,
          const int* __restrict__ mflag,
          float* __restrict__ q, float* __restrict__ outp) {
    GKDEF;
    __shared__ float A[20 * 144];   // t1 halo tile; reused for t2 iff !meq
    __shared__ float B[8 * 144];    // blurV output
    int bid = blockIdx.x;           // grid 3024, XCD-swizzled
    int xcd = bid & 7;
    int idx = bid >> 3;
    int c   = idx % 21;
    int rem = idx / 21;
    int xt  = rem % 3;
    int ytl = rem / 3;
    int gyt = xcd * 6 + ytl;
    int x0 = xt * 128;
    int y0 = gyt * 8;
    bool meq = (mflag[0] != 0);     // uniform branch
    const u16* t1p = t1 + (size_t)c * HW;

    // ---- stage A = t1 halo (zero-padded), bf16 -> fp32 ----
    for (int i = threadIdx.x; i < 20 * 36; i += 256) {
        int r = i / 36, q4 = i - r * 36;
        int gy = y0 - 6 + r;
        int gx = x0 - 8 + q4 * 4;
        float4 v;
        if (gy < 0 || gy >= H) {
            v.x = v.y = v.z = v.w = 0.f;
        } else if (gx >= 0 && gx + 3 < W) {
            ushort4 u = *(const ushort4*)(t1p + gy * W + gx);
            v.x = bfu2f(u.x); v.y = bfu2f(u.y); v.z = bfu2f(u.z); v.w = bfu2f(u.w);
        } else {
            float e[4];
            for (int jj = 0; jj < 4; jj++) {
                int xx = gx + jj;
                e[jj] = (xx >= 0 && xx < W) ? bfu2f(t1p[gy * W + xx]) : 0.f;
            }
            v.x = e[0]; v.y = e[1]; v.z = e[2]; v.w = e[3];
        }
        *(float4*)(A + r * 144 + q4 * 4) = v;
    }
    __syncthreads();

    // ---- blurV (float4): B[r][c4..c4+3] = sum_d gk[d]*A[r+d][c4..c4+3] ----
    for (int i = threadIdx.x; i < 8 * 36; i += 256) {
        int r = i / 36, c4 = (i - r * 36) * 4;
        float ax = 0.f, ay = 0.f, az = 0.f, aw = 0.f;
#pragma unroll
        for (int d = 0; d < 13; d++) {
            const float4 av = *(const float4*)(A + (r + d) * 144 + c4);
            ax += gk[d] * av.x;
            ay += gk[d] * av.y;
            az += gk[d] * av.z;
            aw += gk[d] * av.w;
        }
        float4 o;
        o.x = ax; o.y = ay; o.z = az; o.w = aw;
        *(float4*)(B + r * 144 + c4) = o;
    }
    __syncthreads();

    int row = threadIdx.x >> 5;
    int xq  = (threadIdx.x & 31) * 4;
    int y   = y0 + row;
    int x4  = x0 + xq;
    int p4  = y * W + x4;

    // ---- blurH: 20-float window as 5 aligned b128 (conflict-free) ----
    float bw[20];
    {
        const float* bp = B + row * 144 + xq;
        *(float4*)(bw +  0) = *(const float4*)(bp +  0);
        *(float4*)(bw +  4) = *(const float4*)(bp +  4);
        *(float4*)(bw +  8) = *(const float4*)(bp +  8);
        *(float4*)(bw + 12) = *(const float4*)(bp + 12);
        *(float4*)(bw + 16) = *(const float4*)(bp + 16);
    }
    float sp_[4];
#pragma unroll
    for (int jj = 0; jj < 4; jj++) {
        float a = 0.f;
#pragma unroll
        for (int t = 0; t < 13; t++) a += gk[t] * bw[jj + t + 2];
        sp_[jj] = a;
    }

    int robase;   // bilateral row base in A
    if (meq) {
        robase = row + 6;     // t1 halo rows: gy = y0-6+r  -> r = row-dy+6
    } else {
        // ---- general path: stage t2 tile into A (after blurV barrier) ----
        const u16* t2p = t2 + (size_t)c * HW;
        for (int i = threadIdx.x; i < 12 * 36; i += 256) {
            int r = i / 36, q4 = i - r * 36;
            int gy = min(max(y0 - 2 + r, 0), H - 1);      // clamped; OOB wt 0
            int gx = min(max(x0 - 8 + q4 * 4, 0), W - 4); // clamped; OOB wt 0
            ushort4 u = *(const ushort4*)(t2p + gy * W + gx);
            float4 v;
            v.x = bfu2f(u.x); v.y = bfu2f(u.y); v.z = bfu2f(u.z); v.w = bfu2f(u.w);
            *(float4*)(A + r * 144 + q4 * 4) = v;
        }
        __syncthreads();
        robase = row + 2;     // t2 tile rows: gy = y0-2+r  -> r = row-dy+2
    }

    // ---- bilateral from LDS; tap-pair uint4 loads per dy (3 each) ----
    float bi[4] = {0.f, 0.f, 0.f, 0.f};
    int lb = xq + 8;                        // local col of x4 in the 144-tile
#pragma unroll
    for (int dy = -2; dy <= 2; dy++) {
        const int T0 = (dy + 2) * 5;        // first tap of this row
        const int PR = T0 >> 1;             // first pair stream needed
        uint4 pra = *(const uint4*)(wtab + (size_t)(PR + 0) * HW + p4);
        uint4 prb = *(const uint4*)(wtab + (size_t)(PR + 1) * HW + p4);
        uint4 prc = *(const uint4*)(wtab + (size_t)(PR + 2) * HW + p4);
        int r = robase - dy;
        float rr[12];
        float4 v0 = *(const float4*)(A + r * 144 + lb - 4);
        float4 v1 = *(const float4*)(A + r * 144 + lb);
        float4 v2 = *(const float4*)(A + r * 144 + lb + 4);
        rr[0] = v0.x; rr[1] = v0.y; rr[2]  = v0.z; rr[3]  = v0.w;
        rr[4] = v1.x; rr[5] = v1.y; rr[6]  = v1.z; rr[7]  = v1.w;
        rr[8] = v2.x; rr[9] = v2.y; rr[10] = v2.z; rr[11] = v2.w;
#pragma unroll
        for (int dx = -2; dx <= 2; dx++) {
            const int T   = T0 + dx + 2;    // tap index (compile-time)
            const int pi  = (T >> 1) - PR;  // 0..2
            const int sel = T & 1;
            const uint4 pv = (pi == 0) ? pra : (pi == 1) ? prb : prc;
            bi[0] += pair2f(pv.x, sel) * rr[0 - dx + 4];
            bi[1] += pair2f(pv.y, sel) * rr[1 - dx + 4];
            bi[2] += pair2f(pv.z, sel) * rr[2 - dx + 4];
            bi[3] += pair2f(pv.w, sel) * rr[3 - dx + 4];
        }
    }

    // ---- update-phase loads ----
    float lc = loww[c], hw_ = highw[0];
    float4 msv = *(const float4*)(msum + p4);
    float4 isv = *(const float4*)(inv_sp + p4);
    float4 ibv = *(const float4*)(inv_bn + p4);
    float4 unv = *(const float4*)(unp + (size_t)c * HW + p4);
    float* qp = q + (size_t)c * HW + p4;
    float4 qo4 = *(const float4*)qp;

    // ---- update: q/out = un - pairwise + superpixel closed form ----
    float msa[4] = {msv.x, msv.y, msv.z, msv.w};
    float isa[4] = {isv.x, isv.y, isv.z, isv.w};
    float iba[4] = {ibv.x, ibv.y, ibv.z, ibv.w};
    float qoa[4] = {qo4.x, qo4.y, qo4.z, qo4.w};
    float una[4] = {unv.x, unv.y, unv.z, unv.w};
    float outv[4];
    for (int jj = 0; jj < 4; jj++) {
        float pw = sp_[jj] * isa[jj] + bi[jj] * iba[jj];
        float qo = qoa[jj];
        float ft = (msa[jj] * qo + (NCLIQ - msa[jj])) / qo;
        float su = lc * ft + hw_ * (1.0f - ft);
        outv[jj] = una[jj] - pw + su;
    }
    if (outp) {   // last iteration: write final (H,W,C) layout directly
        for (int jj = 0; jj < 4; jj++)
            outp[(size_t)(p4 + jj) * C + c] = outv[jj];
    } else {
        float4 res;
        res.x = outv[0]; res.y = outv[1]; res.z = outv[2]; res.w = outv[3];
        *(float4*)qp = res;
    }
}

// ---- launch -----------------------------------------------------------------

extern "C" void kernel_launch(void* const* d_in, const int* in_sizes, int n_in,
                              void* d_out, int out_size, void* d_ws, size_t ws_size,
                              hipStream_t stream) {
    const float* un    = (const float*)d_in[0];
    const float* rgb   = (const float*)d_in[1];
    const int*   sp    = (const int*)d_in[2];
    const float* Wsp   = (const float*)d_in[3];
    const float* Wbi   = (const float*)d_in[4];
    const float* Cm    = (const float*)d_in[5];
    const float* loww  = (const float*)d_in[6];
    const float* highw = (const float*)d_in[7];
    float* out = (float*)d_out;

    // ws layout ~46.8 MB
    float* ws    = (float*)d_ws;
    float* q     = ws;                            // C*HW fp32
    float* unp   = q   + (size_t)C * HW;          // C*HW fp32
    float* msum  = unp + (size_t)C * HW;          // HW
    float* isp   = msum + HW;                     // HW
    float* ibn   = isp + HW;                      // HW
    float* M1    = ibn + HW;                      // C*C
    float* M2    = M1 + C * C;                    // C*C
    int*   mflag = (int*)(M2 + C * C);            // 1 (in pad space)
    u16*   t1    = (u16*)(M2 + C * C + 6);        // C*HW bf16 (16B-aligned)
    u16*   t2    = t1 + (size_t)C * HW;           // C*HW bf16
    u32*   wtab  = (u32*)(t2 + (size_t)C * HW);   // 13*HW u32 tap-pairs

    dim3 blk(256);
    dim3 gpix(HW / 128);                 // 1152, 128 px/block, 2 thr/px
    dim3 gVF(3 * 48 * C);                // 3024, 1-D swizzled (R5 form)

    // prep includes iteration 0's ST (B-waves)
    k_prep<<<gpix, blk, 0, stream>>>(un, rgb, sp, Wsp, Wbi, Cm,
                                     q, unp, wtab, msum, isp, ibn, M1, M2,
                                     mflag, t1, t2);
    for (int it = 0; it < 5; it++) {
        k_VF<<<gVF, blk, 0, stream>>>(t1, t2, wtab, msum, isp, ibn,
                                      unp, loww, highw, mflag, q,
                                      (it == 4) ? out : (float*)nullptr);
        if (it < 4)
            k_ST<<<gpix, blk, 0, stream>>>(q, M1, M2, mflag, t1, t2);
    }
}